// Round 1
// baseline (102.056 us; speedup 1.0000x reference)
//
#include <hip/hip_runtime.h>

#define D_MODEL 2048
#define NUM_TILES 64
#define D_SLICE 32
#define TILES_PER_CLUSTER 8
#define NUM_CLUSTERS 8
#define GRID_PTS 16
#define LN_EPS 1e-5f

// order-preserving float<->uint map for atomic min/max
__device__ __forceinline__ unsigned int encF(float f) {
    unsigned int u = __float_as_uint(f);
    return (u & 0x80000000u) ? ~u : (u | 0x80000000u);
}
__device__ __forceinline__ float decF(unsigned int u) {
    unsigned int b = (u & 0x80000000u) ? (u ^ 0x80000000u) : ~u;
    return __uint_as_float(b);
}

// Kernel A: compute slope_sign per dim (flattened: dim d -> slopes[d*16..+16))
// and init the per-tile min/max encodings (ws is poisoned; re-init every call).
__global__ void kan_setup(const float* __restrict__ slopes,
                          float* __restrict__ sgn,
                          unsigned int* __restrict__ tmin,
                          unsigned int* __restrict__ tmax) {
    int d = blockIdx.x * blockDim.x + threadIdx.x;  // 0..2047
    if (d < NUM_TILES) { tmin[d] = 0xFFFFFFFFu; tmax[d] = 0u; }
    if (d < D_MODEL) {
        const float* p = slopes + (size_t)d * GRID_PTS;  // (t*32+j)*16 == d*16
        float s = 0.f;
#pragma unroll
        for (int k = 0; k < GRID_PTS; ++k) s += p[k];
        float m = s * (1.0f / GRID_PTS);
        sgn[d] = (m > 0.f) ? 1.f : ((m < 0.f) ? -1.f : 0.f);
    }
}

// Kernel B: one block per token. LayerNorm (two-pass), integer sign scores,
// cluster+tile argmax (first-wins), out = x copy, stash xn slice, tile stats.
__launch_bounds__(256)
__global__ void kan_main(const float* __restrict__ x,
                         const float* __restrict__ gamma,
                         const float* __restrict__ beta,
                         const float* __restrict__ sgn,
                         float* __restrict__ out,
                         float* __restrict__ xn_slice,
                         int* __restrict__ tidx_out,
                         unsigned int* __restrict__ tmin,
                         unsigned int* __restrict__ tmax) {
    const int n = blockIdx.x;
    const int tid = threadIdx.x;
    const size_t base = (size_t)n * D_MODEL + (size_t)tid * 8;

    // load 8 contiguous dims (all within tile tid>>2)
    float4 a = *(const float4*)(x + base);
    float4 b = *(const float4*)(x + base + 4);
    float xv[8] = {a.x, a.y, a.z, a.w, b.x, b.y, b.z, b.w};

    __shared__ float red[4];
    __shared__ int ts[NUM_TILES];
    __shared__ int chosen;

    // ---- pass 1: mean ----
    float s = 0.f;
#pragma unroll
    for (int k = 0; k < 8; ++k) s += xv[k];
#pragma unroll
    for (int off = 32; off > 0; off >>= 1) s += __shfl_down(s, off);
    if ((tid & 63) == 0) red[tid >> 6] = s;
    __syncthreads();
    float mu = (red[0] + red[1] + red[2] + red[3]) * (1.0f / D_MODEL);
    __syncthreads();

    // ---- pass 2: variance (mean of squared deviations) ----
    float s2 = 0.f;
#pragma unroll
    for (int k = 0; k < 8; ++k) { float dvt = xv[k] - mu; s2 += dvt * dvt; }
#pragma unroll
    for (int off = 32; off > 0; off >>= 1) s2 += __shfl_down(s2, off);
    if ((tid & 63) == 0) red[tid >> 6] = s2;
    __syncthreads();
    float var = (red[0] + red[1] + red[2] + red[3]) * (1.0f / D_MODEL);
    float rs = rsqrtf(var + LN_EPS);

    // ---- normalized values + integer sign score ----
    float4 g0 = *(const float4*)(gamma + tid * 8);
    float4 g1 = *(const float4*)(gamma + tid * 8 + 4);
    float4 b0 = *(const float4*)(beta + tid * 8);
    float4 b1 = *(const float4*)(beta + tid * 8 + 4);
    float4 sg0 = *(const float4*)(sgn + tid * 8);
    float4 sg1 = *(const float4*)(sgn + tid * 8 + 4);
    float gv[8] = {g0.x, g0.y, g0.z, g0.w, g1.x, g1.y, g1.z, g1.w};
    float bv[8] = {b0.x, b0.y, b0.z, b0.w, b1.x, b1.y, b1.z, b1.w};
    float sv[8] = {sg0.x, sg0.y, sg0.z, sg0.w, sg1.x, sg1.y, sg1.z, sg1.w};

    float xn[8];
    int sc = 0;
#pragma unroll
    for (int k = 0; k < 8; ++k) {
        xn[k] = (xv[k] - mu) * rs * gv[k] + bv[k];
        int s1 = (xn[k] > 0.f) ? 1 : ((xn[k] < 0.f) ? -1 : 0);
        sc += s1 * (int)sv[k];
    }
    // reduce over the 4 threads owning one tile (4-aligned lane groups)
    sc += __shfl_xor(sc, 1);
    sc += __shfl_xor(sc, 2);
    if ((tid & 3) == 0) ts[tid >> 2] = sc;
    __syncthreads();

    // ---- serial argmax (first-wins, matches numpy) ----
    if (tid == 0) {
        int bc = 0, bv_ = -2147483647;
#pragma unroll
        for (int c = 0; c < NUM_CLUSTERS; ++c) {
            int cs = 0;
#pragma unroll
            for (int t = 0; t < TILES_PER_CLUSTER; ++t) cs += ts[c * TILES_PER_CLUSTER + t];
            if (cs > bv_) { bv_ = cs; bc = c; }
        }
        int t0 = bc * TILES_PER_CLUSTER;
        int bt = t0, btv = ts[t0];
#pragma unroll
        for (int t = 1; t < TILES_PER_CLUSTER; ++t) {
            if (ts[t0 + t] > btv) { btv = ts[t0 + t]; bt = t0 + t; }
        }
        chosen = bt;
        tidx_out[n] = bt;
    }
    __syncthreads();
    int tile = chosen;

    // ---- out = x copy (full row) ----
    *(float4*)(out + base) = a;
    *(float4*)(out + base + 4) = b;

    // ---- stash xn slice of chosen tile ----
    if ((tid >> 2) == tile) {
        float* q = xn_slice + (size_t)n * D_SLICE + (tid & 3) * 8;
        *(float4*)(q) = make_float4(xn[0], xn[1], xn[2], xn[3]);
        *(float4*)(q + 4) = make_float4(xn[4], xn[5], xn[6], xn[7]);
    }

    // ---- per-tile min/max across its 4 threads; atomic into global stats ----
    float mn8 = xn[0], mx8 = xn[0];
#pragma unroll
    for (int k = 1; k < 8; ++k) { mn8 = fminf(mn8, xn[k]); mx8 = fmaxf(mx8, xn[k]); }
    mn8 = fminf(mn8, __shfl_xor(mn8, 1));
    mn8 = fminf(mn8, __shfl_xor(mn8, 2));
    mx8 = fmaxf(mx8, __shfl_xor(mx8, 1));
    mx8 = fmaxf(mx8, __shfl_xor(mx8, 2));
    if (tid == tile * 4) {
        atomicMin(&tmin[tile], encF(mn8));
        atomicMax(&tmax[tile], encF(mx8));
    }
}

// Kernel C: one thread per (token, j). Spline delta, out += delta on 32 dims.
__global__ void kan_apply(const float* __restrict__ xn_slice,
                          const int* __restrict__ tidx,
                          const float* __restrict__ bases,
                          const float* __restrict__ slopes,
                          const float* __restrict__ oscale,
                          const unsigned int* __restrict__ tmin,
                          const unsigned int* __restrict__ tmax,
                          float* __restrict__ out, int N) {
    int g = blockIdx.x * blockDim.x + threadIdx.x;
    if (g >= N * D_SLICE) return;
    int n = g >> 5;
    int j = g & 31;
    int t = tidx[n];
    float xnv = xn_slice[g];
    float mn = decF(tmin[t]);
    float mx = decF(tmax[t]);
    float u = (xnv - mn) / (mx - mn + 1e-8f);
    u = fminf(fmaxf(u, 0.0f), 1.0f - 1e-6f);
    int gi = (int)(u * (float)GRID_PTS);
    gi = min(max(gi, 0), GRID_PTS - 1);
    int off = (t * D_SLICE + j) * GRID_PTS + gi;
    float bb = bases[off];
    float ss = slopes[off];
    float xl = (u - (float)gi * (1.0f / GRID_PTS)) * (float)GRID_PTS;
    float delta = (bb + ss * xl) * oscale[t];
    size_t oi = (size_t)n * D_MODEL + t * D_SLICE + j;
    out[oi] = out[oi] + delta;
}

extern "C" void kernel_launch(void* const* d_in, const int* in_sizes, int n_in,
                              void* d_out, int out_size, void* d_ws, size_t ws_size,
                              hipStream_t stream) {
    const float* x      = (const float*)d_in[0];
    const float* gamma  = (const float*)d_in[1];
    const float* beta   = (const float*)d_in[2];
    const float* bases  = (const float*)d_in[3];
    const float* slopes = (const float*)d_in[4];
    const float* oscale = (const float*)d_in[5];
    float* out = (float*)d_out;
    const int N = in_sizes[0] / D_MODEL;  // 16384

    // workspace layout
    char* w = (char*)d_ws;
    unsigned int* tmin = (unsigned int*)w; w += 256;
    unsigned int* tmax = (unsigned int*)w; w += 256;
    float* sgn = (float*)w;  w += D_MODEL * sizeof(float);
    int* tidx = (int*)w;     w += (size_t)N * sizeof(int);
    float* xns = (float*)w;  w += (size_t)N * D_SLICE * sizeof(float);

    kan_setup<<<(D_MODEL + 255) / 256, 256, 0, stream>>>(slopes, sgn, tmin, tmax);
    kan_main<<<N, 256, 0, stream>>>(x, gamma, beta, sgn, out, xns, tidx, tmin, tmax);
    kan_apply<<<(N * D_SLICE + 255) / 256, 256, 0, stream>>>(xns, tidx, bases, slopes,
                                                             oscale, tmin, tmax, out, N);
}

// Round 2
// 65.751 us; speedup vs baseline: 1.5522x; 1.5522x over previous
//
#include <hip/hip_runtime.h>

#define D_MODEL 2048
#define NUM_TILES 64
#define D_SLICE 32
#define TILES_PER_CLUSTER 8
#define NUM_CLUSTERS 8
#define GRID_PTS 16
#define LN_EPS 1e-5f
#define NBUCKET 64

// order-preserving float<->uint map for atomic min/max
__device__ __forceinline__ unsigned int encF(float f) {
    unsigned int u = __float_as_uint(f);
    return (u & 0x80000000u) ? ~u : (u | 0x80000000u);
}
__device__ __forceinline__ float decF(unsigned int u) {
    unsigned int b = (u & 0x80000000u) ? (u ^ 0x80000000u) : ~u;
    return __uint_as_float(b);
}

// Kernel A: slope_sign per dim + init bucketed tile min/max (ws is poisoned).
__global__ void kan_setup(const float* __restrict__ slopes,
                          float* __restrict__ sgn,
                          unsigned int* __restrict__ tminb,
                          unsigned int* __restrict__ tmaxb) {
    int d = blockIdx.x * blockDim.x + threadIdx.x;  // 0..4095
    if (d < NUM_TILES * NBUCKET) { tminb[d] = 0xFFFFFFFFu; tmaxb[d] = 0u; }
    if (d < D_MODEL) {
        const float* p = slopes + (size_t)d * GRID_PTS;
        float s = 0.f;
#pragma unroll
        for (int k = 0; k < GRID_PTS; ++k) s += p[k];
        float m = s * (1.0f / GRID_PTS);
        sgn[d] = (m > 0.f) ? 1.f : ((m < 0.f) ? -1.f : 0.f);
    }
}

// Kernel B: one block per token. LayerNorm, integer sign scores, argmax,
// out = x copy, stash xn slice, bucketed tile stats (low-contention atomics).
__launch_bounds__(256)
__global__ void kan_main(const float* __restrict__ x,
                         const float* __restrict__ gamma,
                         const float* __restrict__ beta,
                         const float* __restrict__ sgn,
                         float* __restrict__ out,
                         float* __restrict__ xn_slice,
                         int* __restrict__ tidx_out,
                         unsigned int* __restrict__ tminb,
                         unsigned int* __restrict__ tmaxb) {
    const int n = blockIdx.x;
    const int tid = threadIdx.x;
    const size_t base = (size_t)n * D_MODEL + (size_t)tid * 8;

    float4 a = *(const float4*)(x + base);
    float4 b = *(const float4*)(x + base + 4);
    float xv[8] = {a.x, a.y, a.z, a.w, b.x, b.y, b.z, b.w};

    __shared__ float red[4];
    __shared__ int ts[NUM_TILES];
    __shared__ int cs[NUM_CLUSTERS];
    __shared__ int chosen;

    // ---- pass 1: mean ----
    float s = 0.f;
#pragma unroll
    for (int k = 0; k < 8; ++k) s += xv[k];
#pragma unroll
    for (int off = 32; off > 0; off >>= 1) s += __shfl_down(s, off);
    if ((tid & 63) == 0) red[tid >> 6] = s;
    __syncthreads();
    float mu = (red[0] + red[1] + red[2] + red[3]) * (1.0f / D_MODEL);
    __syncthreads();

    // ---- pass 2: variance ----
    float s2 = 0.f;
#pragma unroll
    for (int k = 0; k < 8; ++k) { float dvt = xv[k] - mu; s2 += dvt * dvt; }
#pragma unroll
    for (int off = 32; off > 0; off >>= 1) s2 += __shfl_down(s2, off);
    if ((tid & 63) == 0) red[tid >> 6] = s2;
    __syncthreads();
    float var = (red[0] + red[1] + red[2] + red[3]) * (1.0f / D_MODEL);
    float rs = rsqrtf(var + LN_EPS);

    // ---- normalized values + integer sign score ----
    float4 g0 = *(const float4*)(gamma + tid * 8);
    float4 g1 = *(const float4*)(gamma + tid * 8 + 4);
    float4 b0 = *(const float4*)(beta + tid * 8);
    float4 b1 = *(const float4*)(beta + tid * 8 + 4);
    float4 sg0 = *(const float4*)(sgn + tid * 8);
    float4 sg1 = *(const float4*)(sgn + tid * 8 + 4);
    float gv[8] = {g0.x, g0.y, g0.z, g0.w, g1.x, g1.y, g1.z, g1.w};
    float bv[8] = {b0.x, b0.y, b0.z, b0.w, b1.x, b1.y, b1.z, b1.w};
    float sv[8] = {sg0.x, sg0.y, sg0.z, sg0.w, sg1.x, sg1.y, sg1.z, sg1.w};

    float xn[8];
    int sc = 0;
#pragma unroll
    for (int k = 0; k < 8; ++k) {
        xn[k] = (xv[k] - mu) * rs * gv[k] + bv[k];
        int s1 = (xn[k] > 0.f) ? 1 : ((xn[k] < 0.f) ? -1 : 0);
        sc += s1 * (int)sv[k];
    }
    sc += __shfl_xor(sc, 1);
    sc += __shfl_xor(sc, 2);
    if ((tid & 3) == 0) ts[tid >> 2] = sc;
    __syncthreads();

    // ---- argmax: 8 threads sum clusters in parallel, thread 0 compares ----
    if (tid < NUM_CLUSTERS) {
        int c = 0;
#pragma unroll
        for (int t = 0; t < TILES_PER_CLUSTER; ++t) c += ts[tid * TILES_PER_CLUSTER + t];
        cs[tid] = c;
    }
    __syncthreads();
    if (tid == 0) {
        int bc = 0, bv_ = -2147483647;
#pragma unroll
        for (int c = 0; c < NUM_CLUSTERS; ++c)
            if (cs[c] > bv_) { bv_ = cs[c]; bc = c; }
        int t0 = bc * TILES_PER_CLUSTER;
        int bt = t0, btv = ts[t0];
#pragma unroll
        for (int t = 1; t < TILES_PER_CLUSTER; ++t)
            if (ts[t0 + t] > btv) { btv = ts[t0 + t]; bt = t0 + t; }
        chosen = bt;
        tidx_out[n] = bt;
    }
    __syncthreads();
    int tile = chosen;

    // ---- out = x copy ----
    *(float4*)(out + base) = a;
    *(float4*)(out + base + 4) = b;

    // ---- stash xn slice of chosen tile ----
    if ((tid >> 2) == tile) {
        float* q = xn_slice + (size_t)n * D_SLICE + (tid & 3) * 8;
        *(float4*)(q) = make_float4(xn[0], xn[1], xn[2], xn[3]);
        *(float4*)(q + 4) = make_float4(xn[4], xn[5], xn[6], xn[7]);
    }

    // ---- chosen-tile min/max -> bucketed atomics (contention / 64) ----
    float mn8 = xn[0], mx8 = xn[0];
#pragma unroll
    for (int k = 1; k < 8; ++k) { mn8 = fminf(mn8, xn[k]); mx8 = fmaxf(mx8, xn[k]); }
    mn8 = fminf(mn8, __shfl_xor(mn8, 1));
    mn8 = fminf(mn8, __shfl_xor(mn8, 2));
    mx8 = fmaxf(mx8, __shfl_xor(mx8, 1));
    mx8 = fmaxf(mx8, __shfl_xor(mx8, 2));
    if (tid == tile * 4) {
        int bkt = blockIdx.x & (NBUCKET - 1);
        atomicMin(&tminb[tile * NBUCKET + bkt], encF(mn8));
        atomicMax(&tmaxb[tile * NBUCKET + bkt], encF(mx8));
    }
}

// Kernel B2: reduce 64 buckets -> final per-tile min/max. One block, 64 thr.
__global__ void kan_reduce(const unsigned int* __restrict__ tminb,
                           const unsigned int* __restrict__ tmaxb,
                           unsigned int* __restrict__ tmin,
                           unsigned int* __restrict__ tmax) {
    int t = threadIdx.x;  // 0..63
    unsigned int mn = 0xFFFFFFFFu, mx = 0u;
#pragma unroll 4
    for (int b = 0; b < NBUCKET; ++b) {
        mn = min(mn, tminb[t * NBUCKET + b]);
        mx = max(mx, tmaxb[t * NBUCKET + b]);
    }
    tmin[t] = mn;
    tmax[t] = mx;
}

// Kernel C: one thread per (token, j). Spline delta, out += delta.
__global__ void kan_apply(const float* __restrict__ xn_slice,
                          const int* __restrict__ tidx,
                          const float* __restrict__ bases,
                          const float* __restrict__ slopes,
                          const float* __restrict__ oscale,
                          const unsigned int* __restrict__ tmin,
                          const unsigned int* __restrict__ tmax,
                          float* __restrict__ out, int N) {
    int g = blockIdx.x * blockDim.x + threadIdx.x;
    if (g >= N * D_SLICE) return;
    int n = g >> 5;
    int j = g & 31;
    int t = tidx[n];
    float xnv = xn_slice[g];
    float mn = decF(tmin[t]);
    float mx = decF(tmax[t]);
    float u = (xnv - mn) / (mx - mn + 1e-8f);
    u = fminf(fmaxf(u, 0.0f), 1.0f - 1e-6f);
    int gi = (int)(u * (float)GRID_PTS);
    gi = min(max(gi, 0), GRID_PTS - 1);
    int off = (t * D_SLICE + j) * GRID_PTS + gi;
    float bb = bases[off];
    float ss = slopes[off];
    float xl = (u - (float)gi * (1.0f / GRID_PTS)) * (float)GRID_PTS;
    float delta = (bb + ss * xl) * oscale[t];
    size_t oi = (size_t)n * D_MODEL + t * D_SLICE + j;
    out[oi] = out[oi] + delta;
}

extern "C" void kernel_launch(void* const* d_in, const int* in_sizes, int n_in,
                              void* d_out, int out_size, void* d_ws, size_t ws_size,
                              hipStream_t stream) {
    const float* x      = (const float*)d_in[0];
    const float* gamma  = (const float*)d_in[1];
    const float* beta   = (const float*)d_in[2];
    const float* bases  = (const float*)d_in[3];
    const float* slopes = (const float*)d_in[4];
    const float* oscale = (const float*)d_in[5];
    float* out = (float*)d_out;
    const int N = in_sizes[0] / D_MODEL;  // 16384

    // workspace layout
    char* w = (char*)d_ws;
    unsigned int* tminb = (unsigned int*)w; w += NUM_TILES * NBUCKET * 4;
    unsigned int* tmaxb = (unsigned int*)w; w += NUM_TILES * NBUCKET * 4;
    unsigned int* tmin  = (unsigned int*)w; w += 256;
    unsigned int* tmax  = (unsigned int*)w; w += 256;
    float* sgn = (float*)w;  w += D_MODEL * sizeof(float);
    int* tidx = (int*)w;     w += (size_t)N * sizeof(int);
    float* xns = (float*)w;  w += (size_t)N * D_SLICE * sizeof(float);

    kan_setup<<<(NUM_TILES * NBUCKET + 255) / 256, 256, 0, stream>>>(slopes, sgn, tminb, tmaxb);
    kan_main<<<N, 256, 0, stream>>>(x, gamma, beta, sgn, out, xns, tidx, tminb, tmaxb);
    kan_reduce<<<1, 64, 0, stream>>>(tminb, tmaxb, tmin, tmax);
    kan_apply<<<(N * D_SLICE + 255) / 256, 256, 0, stream>>>(xns, tidx, bases, slopes,
                                                             oscale, tmin, tmax, out, N);
}